// Round 7
// baseline (240.547 us; speedup 1.0000x reference)
//
#include <hip/hip_runtime.h>
#include <math.h>

#define HDIM 4096
#define NEXP 64
#define NTOK 8192
#define KSPLIT 4
#define KSLICE (HDIM / KSPLIT)   // 1024
#define NCHUNK (KSLICE / 32)     // 32 chunks of K=32 per slice
#define NKC (HDIM / 32)          // 128 global k-chunks
#define AUXF 1024                // floats reserved for 8 auxbuf copies
#define TPW 2                    // tokens per wave in topk_k
// B-split layout (shorts): [term][kc 128][quad 4][n 64][8]
#define BT_TERM (NKC * 4 * 64 * 8)  // 262144 shorts per term
#define BT_KC (4 * 64 * 8)          // 2048 shorts per k-chunk

typedef short short8 __attribute__((ext_vector_type(8)));
typedef float f32x4 __attribute__((ext_vector_type(4)));

union i4s8 { int4 i; short8 s; };

// Exact 3-way bf16 split of two fp32 values, packed as (lo16=x0, hi16=x1).
__device__ __forceinline__ void split2x3(float x0, float x1, int& h, int& md, int& lo) {
  unsigned u0 = __float_as_uint(x0), u1 = __float_as_uint(x1);
  unsigned h0 = u0 & 0xFFFF0000u, h1 = u1 & 0xFFFF0000u;
  float r0 = x0 - __uint_as_float(h0);
  float r1 = x1 - __uint_as_float(h1);
  unsigned m0 = __float_as_uint(r0) & 0xFFFF0000u;
  unsigned m1 = __float_as_uint(r1) & 0xFFFF0000u;
  float s0 = r0 - __uint_as_float(m0);
  float s1 = r1 - __uint_as_float(m1);
  h  = (int)((h0 >> 16) | h1);
  md = (int)((m0 >> 16) | m1);
  lo = (int)((__float_as_uint(s0) >> 16) | (__float_as_uint(s1) & 0xFFFF0000u));
}

__device__ __forceinline__ void split8v(const f32x4& p0, const f32x4& p1,
                                        short8& h8, short8& m8, short8& l8) {
  i4s8 h, m, l;
  split2x3(p0.x, p0.y, h.i.x, m.i.x, l.i.x);
  split2x3(p0.z, p0.w, h.i.y, m.i.y, l.i.y);
  split2x3(p1.x, p1.y, h.i.z, m.i.z, l.i.z);
  split2x3(p1.z, p1.w, h.i.w, m.i.w, l.i.w);
  h8 = h.s; m8 = m.s; l8 = l.s;
}

// ---------------------------------------------------------------------------
// Prep: (a) blocks 0..127 pre-split W (64x4096 fp32) into MFMA-fragment-
// ordered bf16x3 terms; (b) block 128 zeroes the aux accumulators.
// ---------------------------------------------------------------------------
__global__ __launch_bounds__(256) void prep_k(const float* __restrict__ W,
                                              short* __restrict__ Bs,
                                              float* __restrict__ auxbuf) {
  if (blockIdx.x == 128) {
#pragma unroll
    for (int j = 0; j < 4; ++j) auxbuf[j * 256 + threadIdx.x] = 0.f;
    return;
  }
  const int g = blockIdx.x * 256 + threadIdx.x;  // 0..32767
  const int n = g >> 9;                          // expert 0..63
  const int k8 = g & 511;                        // 8-k group
  const f32x4 p0 = *(const f32x4*)&W[(size_t)n * HDIM + k8 * 8];
  const f32x4 p1 = *(const f32x4*)&W[(size_t)n * HDIM + k8 * 8 + 4];
  short8 h8, m8, l8;
  split8v(p0, p1, h8, m8, l8);
  const int kc = k8 >> 2, quad = k8 & 3;
  const size_t o = (((size_t)kc * 4 + quad) * 64 + n) * 8;
  *(short8*)&Bs[o] = h8;
  *(short8*)&Bs[o + BT_TERM] = m8;
  *(short8*)&Bs[o + 2 * BT_TERM] = l8;
}

__device__ __forceinline__ f32x4 ntload4(const float* p) {
  return __builtin_nontemporal_load((const f32x4*)p);
}

__device__ __forceinline__ void loadB(const short* bc, short8* b) {
#pragma unroll
  for (int nt = 0; nt < 4; ++nt) {
    b[nt]     = *(const short8*)(bc + nt * 128);               // hi
    b[4 + nt] = *(const short8*)(bc + nt * 128 + BT_TERM);     // mid
    b[8 + nt] = *(const short8*)(bc + nt * 128 + 2 * BT_TERM); // lo
  }
}

// ---------------------------------------------------------------------------
// LDS-free GEMM, latency-tuned: A loads non-temporal (no L2 allocate -> B
// stays L2-resident, not thrashed by the 134 MB A stream); B fragments kept
// in a register double-buffer, software-pipelined ONE CHUNK AHEAD so their
// ~200-cyc L2 latency is covered by the previous chunk's 24 MFMAs + split.
// M=16/wave, N=64, KSPLIT=4 -> 512 blocks = 2/CU, all resident, no tail.
// ---------------------------------------------------------------------------
__global__ __launch_bounds__(256, 3) void gemm_k(const float* __restrict__ A,
                                                 const short* __restrict__ Bs,
                                                 float* __restrict__ Lp,
                                                 int atomic_mode) {
  const int tid = threadIdx.x;
  const int wave = tid >> 6, lane = tid & 63;
  const int l15 = lane & 15, quad = lane >> 4;
  const int m_base = blockIdx.x * 64 + wave * 16;
  const int kb = blockIdx.y;
  float* Lout = Lp + (atomic_mode ? (size_t)0 : (size_t)kb * NTOK * NEXP);

  const float* a0 = A + (size_t)(m_base + l15) * HDIM + kb * KSLICE + quad * 8;
  const short* bbase = Bs + ((size_t)(kb * NCHUNK) * 4 + quad) * 512 + l15 * 8;

  f32x4 acc[4];
#pragma unroll
  for (int nt = 0; nt < 4; ++nt) acc[nt] = (f32x4){0.f, 0.f, 0.f, 0.f};

  short8 B[2][12];     // double-buffered B fragments (one chunk in flight)
  f32x4 ra[2][2];      // A raw, two chunks in flight
  short8 fa[3];

  loadB(bbase, B[0]);
  ra[0][0] = ntload4(a0);
  ra[0][1] = ntload4(a0 + 4);
  ra[1][0] = ntload4(a0 + 32);
  ra[1][1] = ntload4(a0 + 36);

#pragma unroll 2
  for (int i = 0; i < NCHUNK; ++i) {
    const int cur = i & 1;
    // 1) B prefetch for chunk i+1 (issued before anything consumes vmem)
    const int ip1 = (i + 1 < NCHUNK) ? i + 1 : i;
    loadB(bbase + (size_t)ip1 * BT_KC, B[cur ^ 1]);
    // 2) split A chunk i (ra[cur] was loaded 2 chunks ago — long in flight)
    split8v(ra[cur][0], ra[cur][1], fa[0], fa[1], fa[2]);
    // 3) A prefetch chunk i+2 into the regs split just freed (non-temporal)
    if (i + 2 < NCHUNK) {
      ra[cur][0] = ntload4(a0 + (i + 2) * 32);
      ra[cur][1] = ntload4(a0 + (i + 2) * 32 + 4);
    }
    // 4) MFMA chunk i with B[cur] (loaded during chunk i-1 -> latency hidden)
#pragma unroll
    for (int nt = 0; nt < 4; ++nt) {
      f32x4 c = acc[nt];
      c = __builtin_amdgcn_mfma_f32_16x16x32_bf16(fa[0], B[cur][nt], c, 0, 0, 0);
      c = __builtin_amdgcn_mfma_f32_16x16x32_bf16(fa[0], B[cur][4 + nt], c, 0, 0, 0);
      c = __builtin_amdgcn_mfma_f32_16x16x32_bf16(fa[1], B[cur][nt], c, 0, 0, 0);
      c = __builtin_amdgcn_mfma_f32_16x16x32_bf16(fa[0], B[cur][8 + nt], c, 0, 0, 0);
      c = __builtin_amdgcn_mfma_f32_16x16x32_bf16(fa[2], B[cur][nt], c, 0, 0, 0);
      c = __builtin_amdgcn_mfma_f32_16x16x32_bf16(fa[1], B[cur][4 + nt], c, 0, 0, 0);
      acc[nt] = c;
    }
  }

#pragma unroll
  for (int nt = 0; nt < 4; ++nt)
#pragma unroll
    for (int r = 0; r < 4; ++r) {
      const int m = m_base + quad * 4 + r;
      const int n = nt * 16 + l15;
      if (atomic_mode) atomicAdd(&Lout[(size_t)m * NEXP + n], acc[nt][r]);
      else Lout[(size_t)m * NEXP + n] = acc[nt][r];
    }
}

// ---------------------------------------------------------------------------
// Top-k router, wave-per-token (lane = expert). rank via stable count,
// winners scatter via ds_permute. (unchanged — ~8 us)
// ---------------------------------------------------------------------------
__global__ __launch_bounds__(256) void topk_k(const float* __restrict__ Lp, int nsl,
                                              float* __restrict__ out,
                                              float* __restrict__ auxbuf) {
  __shared__ float sl[4][64];
  __shared__ float s_aux[128];
  const int tid = threadIdx.x;
  const int wave = tid >> 6, lane = tid & 63;
  if (tid < 128) s_aux[tid] = 0.f;
  __syncthreads();

  for (int it = 0; it < TPW; ++it) {
    const int t = (blockIdx.x * 4 + wave) * TPW + it;
    float x = 0.f;
    for (int s = 0; s < nsl; ++s)
      x += Lp[(size_t)s * (NTOK * NEXP) + (size_t)t * NEXP + lane];
    sl[wave][lane] = x;

    float mx = x;
#pragma unroll
    for (int off = 32; off >= 1; off >>= 1)
      mx = fmaxf(mx, __shfl_xor(mx, off, 64));
    const float e = __expf(x - mx);
    float ssum = e;
#pragma unroll
    for (int off = 32; off >= 1; off >>= 1) ssum += __shfl_xor(ssum, off, 64);
    const float prob = e / ssum;

    __syncthreads();

    int cnt = 0;
#pragma unroll
    for (int c = 0; c < 4; ++c) {
      const float4 v0 = *(const float4*)&sl[wave][c * 16 + 0];
      const float4 v1 = *(const float4*)&sl[wave][c * 16 + 4];
      const float4 v2 = *(const float4*)&sl[wave][c * 16 + 8];
      const float4 v3 = *(const float4*)&sl[wave][c * 16 + 12];
      const float xv[16] = {v0.x, v0.y, v0.z, v0.w, v1.x, v1.y, v1.z, v1.w,
                            v2.x, v2.y, v2.z, v2.w, v3.x, v3.y, v3.z, v3.w};
#pragma unroll
      for (int j = 0; j < 16; ++j) {
        const int jj = c * 16 + j;
        cnt += (xv[j] > x) || (xv[j] == x && jj < lane);
      }
    }

    float tp = (cnt < 8) ? prob : 0.f;
    float tsum = tp;
#pragma unroll
    for (int off = 32; off >= 1; off >>= 1) tsum += __shfl_xor(tsum, off, 64);

    const int dst = cnt << 2;
    const float pv = __uint_as_float(
        (unsigned)__builtin_amdgcn_ds_permute(dst, (int)__float_as_uint(prob)));
    const int pi = __builtin_amdgcn_ds_permute(dst, lane);
    if (lane < 8) {
      out[(size_t)t * 8 + lane] = pv / tsum;
      out[(size_t)NTOK * 8 + (size_t)t * 8 + lane] = (float)pi;
    }
    atomicAdd(&s_aux[lane], prob);
    if (cnt < 8) atomicAdd(&s_aux[64 + lane], 1.f);
  }
  __syncthreads();
  if (tid < 128) atomicAdd(&auxbuf[(blockIdx.x & 7) * 128 + tid], s_aux[tid]);
}

// aux = E * sum_e (count_e/(T*K)) * (sumprob_e/T), over 8 auxbuf copies
__global__ void aux_k(const float* __restrict__ auxbuf, float* __restrict__ out) {
  const int e = threadIdx.x;
  float p = 0.f, f = 0.f;
#pragma unroll
  for (int c = 0; c < 8; ++c) {
    p += auxbuf[c * 128 + e];
    f += auxbuf[c * 128 + 64 + e];
  }
  p *= (1.f / (float)NTOK);
  f *= (1.f / ((float)NTOK * 8.f));
  float v = f * p;
#pragma unroll
  for (int off = 32; off >= 1; off >>= 1) v += __shfl_xor(v, off, 64);
  if (e == 0) out[2 * NTOK * 8] = 64.f * v;
}

extern "C" void kernel_launch(void* const* d_in, const int* in_sizes, int n_in,
                              void* d_out, int out_size, void* d_ws, size_t ws_size,
                              hipStream_t stream) {
  const float* hidden = (const float*)d_in[0];  // 8192 x 4096 fp32
  const float* gate = (const float*)d_in[1];    // 64 x 4096 fp32
  float* out = (float*)d_out;                   // [w 65536 | idx 65536 | aux 1]
  float* ws = (float*)d_ws;
  float* auxbuf = ws;  // 8 copies x 128 floats

  const size_t full_need =
      (size_t)AUXF * 4 + (size_t)KSPLIT * NTOK * NEXP * 4 + (size_t)3 * BT_TERM * 2 + 4096;
  const int atomic_mode = (ws_size < full_need) ? 1 : 0;
  const int nsl = atomic_mode ? 1 : KSPLIT;
  float* slices = ws + AUXF;
  short* Bs = (short*)(ws + AUXF + (size_t)nsl * NTOK * NEXP);

  if (atomic_mode)
    (void)hipMemsetAsync(slices, 0, (size_t)NTOK * NEXP * 4, stream);

  prep_k<<<129, 256, 0, stream>>>(gate, Bs, auxbuf);
  gemm_k<<<dim3(128, KSPLIT), 256, 0, stream>>>(hidden, Bs, slices, atomic_mode);
  topk_k<<<NTOK / (4 * TPW), 256, 0, stream>>>(slices, nsl, out, auxbuf);
  aux_k<<<1, 64, 0, stream>>>(auxbuf, out);
}

// Round 8
// 221.425 us; speedup vs baseline: 1.0864x; 1.0864x over previous
//
#include <hip/hip_runtime.h>
#include <math.h>

#define HDIM 4096
#define NEXP 64
#define NTOK 8192
#define KSPLIT 8
#define KSLICE (HDIM / KSPLIT)   // 512
#define NCHUNK (KSLICE / 32)     // 16 chunks of K=32 per slice
#define NKC (HDIM / 32)          // 128 global k-chunks
#define AUXF 1024                // floats reserved for 8 auxbuf copies
#define TPW 2                    // tokens per wave in topk_k
// B-split layout (shorts): [term][kc 128][quad 4][n 64][8]
#define BT_TERM (NKC * 4 * 64 * 8)  // 262144 shorts per term
#define BT_KC (4 * 64 * 8)          // 2048 shorts per k-chunk

typedef short short8 __attribute__((ext_vector_type(8)));
typedef float f32x4 __attribute__((ext_vector_type(4)));

union i4s8 { int4 i; short8 s; };

// Exact 3-way bf16 split of two fp32 values, packed as (lo16=x0, hi16=x1).
__device__ __forceinline__ void split2x3(float x0, float x1, int& h, int& md, int& lo) {
  unsigned u0 = __float_as_uint(x0), u1 = __float_as_uint(x1);
  unsigned h0 = u0 & 0xFFFF0000u, h1 = u1 & 0xFFFF0000u;
  float r0 = x0 - __uint_as_float(h0);
  float r1 = x1 - __uint_as_float(h1);
  unsigned m0 = __float_as_uint(r0) & 0xFFFF0000u;
  unsigned m1 = __float_as_uint(r1) & 0xFFFF0000u;
  float s0 = r0 - __uint_as_float(m0);
  float s1 = r1 - __uint_as_float(m1);
  h  = (int)((h0 >> 16) | h1);
  md = (int)((m0 >> 16) | m1);
  lo = (int)((__float_as_uint(s0) >> 16) | (__float_as_uint(s1) & 0xFFFF0000u));
}

__device__ __forceinline__ void split8v(const f32x4& p0, const f32x4& p1,
                                        short8& h8, short8& m8, short8& l8) {
  i4s8 h, m, l;
  split2x3(p0.x, p0.y, h.i.x, m.i.x, l.i.x);
  split2x3(p0.z, p0.w, h.i.y, m.i.y, l.i.y);
  split2x3(p1.x, p1.y, h.i.z, m.i.z, l.i.z);
  split2x3(p1.z, p1.w, h.i.w, m.i.w, l.i.w);
  h8 = h.s; m8 = m.s; l8 = l.s;
}

__device__ __forceinline__ f32x4 ntload4(const float* p) {
  return __builtin_nontemporal_load((const f32x4*)p);
}

// async global->LDS DMA, 16 B per lane (LDS dest = wave-uniform base + lane*16)
__device__ __forceinline__ void cp16(const void* g, void* l) {
  __builtin_amdgcn_global_load_lds(
      (const __attribute__((address_space(1))) unsigned int*)g,
      (__attribute__((address_space(3))) unsigned int*)l, 16, 0, 0);
}

// ---------------------------------------------------------------------------
// Prep: (a) blocks 0..127 pre-split W (64x4096 fp32) into MFMA-fragment-
// ordered bf16x3 terms; (b) block 128 zeroes the aux accumulators.
// ---------------------------------------------------------------------------
__global__ __launch_bounds__(256) void prep_k(const float* __restrict__ W,
                                              short* __restrict__ Bs,
                                              float* __restrict__ auxbuf) {
  if (blockIdx.x == 128) {
#pragma unroll
    for (int j = 0; j < 4; ++j) auxbuf[j * 256 + threadIdx.x] = 0.f;
    return;
  }
  const int g = blockIdx.x * 256 + threadIdx.x;  // 0..32767
  const int n = g >> 9;                          // expert 0..63
  const int k8 = g & 511;                        // 8-k group
  const f32x4 p0 = *(const f32x4*)&W[(size_t)n * HDIM + k8 * 8];
  const f32x4 p1 = *(const f32x4*)&W[(size_t)n * HDIM + k8 * 8 + 4];
  short8 h8, m8, l8;
  split8v(p0, p1, h8, m8, l8);
  const int kc = k8 >> 2, quad = k8 & 3;
  const size_t o = (((size_t)kc * 4 + quad) * 64 + n) * 8;
  *(short8*)&Bs[o] = h8;
  *(short8*)&Bs[o + BT_TERM] = m8;
  *(short8*)&Bs[o + 2 * BT_TERM] = l8;
}

// ---------------------------------------------------------------------------
// GEMM, m97-style: B chunk (12 KB, pre-split bf16x3 fragments) staged into
// double-buffered LDS via global_load_lds DMA (no VGPR cost, deep queue),
// one barrier per chunk; consumers ds_read_b128 the exact staged layout
// (2-way bank alias only = free). A stays in registers, non-temporal,
// 2 chunks ahead. M=16/wave, N=64; grid (128,8)=1024 blocks = 4/CU resident
// (LDS 24.6 KB/block), 16 waves/CU — barrier drains hidden by the other 3
// independent blocks.
// ---------------------------------------------------------------------------
__global__ __launch_bounds__(256, 4) void gemm_k(const float* __restrict__ A,
                                                 const short* __restrict__ Bs,
                                                 float* __restrict__ Lp,
                                                 int atomic_mode) {
  // [buf][term 3][quad 4][n 64][8 shorts] = 6144 shorts = 12 KB per buffer
  __shared__ __align__(16) short Blds[2][6144];
  const int tid = threadIdx.x;
  const int wave = tid >> 6, lane = tid & 63;
  const int l15 = lane & 15, quad = lane >> 4;
  const int m_base = blockIdx.x * 64 + wave * 16;
  const int kb = blockIdx.y;
  float* Lout = Lp + (atomic_mode ? (size_t)0 : (size_t)kb * NTOK * NEXP);

  const float* a0 = A + (size_t)(m_base + l15) * HDIM + kb * KSLICE + quad * 8;
  // staging source: element (kc, quad=wave, n=lane), term j
  const short* bsrc = Bs + (size_t)(kb * NCHUNK) * BT_KC + (wave * 64 + lane) * 8;

  f32x4 acc[4];
#pragma unroll
  for (int nt = 0; nt < 4; ++nt) acc[nt] = (f32x4){0.f, 0.f, 0.f, 0.f};

  f32x4 ra[2][2];
  short8 fa[3];

  auto stageB = [&](int buf, int i) {
#pragma unroll
    for (int j = 0; j < 3; ++j)
      cp16(bsrc + (size_t)j * BT_TERM + (size_t)i * BT_KC,
           &Blds[buf][(j * 4 + wave) * 512]);
  };
  auto loadA = [&](int buf, int i) {
    ra[buf][0] = ntload4(a0 + i * 32);
    ra[buf][1] = ntload4(a0 + i * 32 + 4);
  };

  stageB(0, 0);
  loadA(0, 0);
  loadA(1, 1);
  __syncthreads();  // chunk-0 staging complete (vmcnt drained)

#pragma unroll 2
  for (int i = 0; i < NCHUNK; ++i) {
    const int cur = i & 1;
    // 1) async-stage next B chunk into the other buffer (safe: everyone
    //    passed the previous barrier, so no one still reads buf cur^1)
    if (i + 1 < NCHUNK) stageB(cur ^ 1, i + 1);
    // 2) split A chunk i (loaded 2 chunks ago — long in flight)
    split8v(ra[cur][0], ra[cur][1], fa[0], fa[1], fa[2]);
    // 3) A prefetch chunk i+2 into freed regs (non-temporal)
    if (i + 2 < NCHUNK) loadA(cur, i + 2);
    // 4) consume chunk i from LDS + MFMA
    const int fo = quad * 512 + l15 * 8;
#pragma unroll
    for (int nt = 0; nt < 4; ++nt) {
      const short8 bh = *(const short8*)&Blds[cur][fo + nt * 128];
      const short8 bm = *(const short8*)&Blds[cur][2048 + fo + nt * 128];
      const short8 bl = *(const short8*)&Blds[cur][4096 + fo + nt * 128];
      f32x4 c = acc[nt];
      c = __builtin_amdgcn_mfma_f32_16x16x32_bf16(fa[0], bh, c, 0, 0, 0);
      c = __builtin_amdgcn_mfma_f32_16x16x32_bf16(fa[0], bm, c, 0, 0, 0);
      c = __builtin_amdgcn_mfma_f32_16x16x32_bf16(fa[1], bh, c, 0, 0, 0);
      c = __builtin_amdgcn_mfma_f32_16x16x32_bf16(fa[0], bl, c, 0, 0, 0);
      c = __builtin_amdgcn_mfma_f32_16x16x32_bf16(fa[2], bh, c, 0, 0, 0);
      c = __builtin_amdgcn_mfma_f32_16x16x32_bf16(fa[1], bm, c, 0, 0, 0);
      acc[nt] = c;
    }
    // 5) barrier: chunk i reads done everywhere + chunk i+1 staging complete
    __syncthreads();
  }

#pragma unroll
  for (int nt = 0; nt < 4; ++nt)
#pragma unroll
    for (int r = 0; r < 4; ++r) {
      const int m = m_base + quad * 4 + r;
      const int n = nt * 16 + l15;
      if (atomic_mode) atomicAdd(&Lout[(size_t)m * NEXP + n], acc[nt][r]);
      else Lout[(size_t)m * NEXP + n] = acc[nt][r];
    }
}

// ---------------------------------------------------------------------------
// Top-k router, wave-per-token (lane = expert). rank via stable count,
// winners scatter via ds_permute. (unchanged — ~8 us)
// ---------------------------------------------------------------------------
__global__ __launch_bounds__(256) void topk_k(const float* __restrict__ Lp, int nsl,
                                              float* __restrict__ out,
                                              float* __restrict__ auxbuf) {
  __shared__ float sl[4][64];
  __shared__ float s_aux[128];
  const int tid = threadIdx.x;
  const int wave = tid >> 6, lane = tid & 63;
  if (tid < 128) s_aux[tid] = 0.f;
  __syncthreads();

  for (int it = 0; it < TPW; ++it) {
    const int t = (blockIdx.x * 4 + wave) * TPW + it;
    float x = 0.f;
    for (int s = 0; s < nsl; ++s)
      x += Lp[(size_t)s * (NTOK * NEXP) + (size_t)t * NEXP + lane];
    sl[wave][lane] = x;

    float mx = x;
#pragma unroll
    for (int off = 32; off >= 1; off >>= 1)
      mx = fmaxf(mx, __shfl_xor(mx, off, 64));
    const float e = __expf(x - mx);
    float ssum = e;
#pragma unroll
    for (int off = 32; off >= 1; off >>= 1) ssum += __shfl_xor(ssum, off, 64);
    const float prob = e / ssum;

    __syncthreads();

    int cnt = 0;
#pragma unroll
    for (int c = 0; c < 4; ++c) {
      const float4 v0 = *(const float4*)&sl[wave][c * 16 + 0];
      const float4 v1 = *(const float4*)&sl[wave][c * 16 + 4];
      const float4 v2 = *(const float4*)&sl[wave][c * 16 + 8];
      const float4 v3 = *(const float4*)&sl[wave][c * 16 + 12];
      const float xv[16] = {v0.x, v0.y, v0.z, v0.w, v1.x, v1.y, v1.z, v1.w,
                            v2.x, v2.y, v2.z, v2.w, v3.x, v3.y, v3.z, v3.w};
#pragma unroll
      for (int j = 0; j < 16; ++j) {
        const int jj = c * 16 + j;
        cnt += (xv[j] > x) || (xv[j] == x && jj < lane);
      }
    }

    float tp = (cnt < 8) ? prob : 0.f;
    float tsum = tp;
#pragma unroll
    for (int off = 32; off >= 1; off >>= 1) tsum += __shfl_xor(tsum, off, 64);

    const int dst = cnt << 2;
    const float pv = __uint_as_float(
        (unsigned)__builtin_amdgcn_ds_permute(dst, (int)__float_as_uint(prob)));
    const int pi = __builtin_amdgcn_ds_permute(dst, lane);
    if (lane < 8) {
      out[(size_t)t * 8 + lane] = pv / tsum;
      out[(size_t)NTOK * 8 + (size_t)t * 8 + lane] = (float)pi;
    }
    atomicAdd(&s_aux[lane], prob);
    if (cnt < 8) atomicAdd(&s_aux[64 + lane], 1.f);
  }
  __syncthreads();
  if (tid < 128) atomicAdd(&auxbuf[(blockIdx.x & 7) * 128 + tid], s_aux[tid]);
}

// aux = E * sum_e (count_e/(T*K)) * (sumprob_e/T), over 8 auxbuf copies
__global__ void aux_k(const float* __restrict__ auxbuf, float* __restrict__ out) {
  const int e = threadIdx.x;
  float p = 0.f, f = 0.f;
#pragma unroll
  for (int c = 0; c < 8; ++c) {
    p += auxbuf[c * 128 + e];
    f += auxbuf[c * 128 + 64 + e];
  }
  p *= (1.f / (float)NTOK);
  f *= (1.f / ((float)NTOK * 8.f));
  float v = f * p;
#pragma unroll
  for (int off = 32; off >= 1; off >>= 1) v += __shfl_xor(v, off, 64);
  if (e == 0) out[2 * NTOK * 8] = 64.f * v;
}

extern "C" void kernel_launch(void* const* d_in, const int* in_sizes, int n_in,
                              void* d_out, int out_size, void* d_ws, size_t ws_size,
                              hipStream_t stream) {
  const float* hidden = (const float*)d_in[0];  // 8192 x 4096 fp32
  const float* gate = (const float*)d_in[1];    // 64 x 4096 fp32
  float* out = (float*)d_out;                   // [w 65536 | idx 65536 | aux 1]
  float* ws = (float*)d_ws;
  float* auxbuf = ws;  // 8 copies x 128 floats

  const size_t full_need =
      (size_t)AUXF * 4 + (size_t)KSPLIT * NTOK * NEXP * 4 + (size_t)3 * BT_TERM * 2 + 4096;
  const int atomic_mode = (ws_size < full_need) ? 1 : 0;
  const int nsl = atomic_mode ? 1 : KSPLIT;
  float* slices = ws + AUXF;
  short* Bs = (short*)(ws + AUXF + (size_t)nsl * NTOK * NEXP);

  if (atomic_mode)
    (void)hipMemsetAsync(slices, 0, (size_t)NTOK * NEXP * 4, stream);

  prep_k<<<129, 256, 0, stream>>>(gate, Bs, auxbuf);
  gemm_k<<<dim3(128, KSPLIT), 256, 0, stream>>>(hidden, Bs, slices, atomic_mode);
  topk_k<<<NTOK / (4 * TPW), 256, 0, stream>>>(slices, nsl, out, auxbuf);
  aux_k<<<1, 64, 0, stream>>>(auxbuf, out);
}